// Round 9
// baseline (121.377 us; speedup 1.0000x reference)
//
#include <hip/hip_runtime.h>
#include <hip/hip_bf16.h>
#include <math.h>

// MultiHeadAttentionQuantum, B=2048 S=1 E=1024 H=128 DK=NW=8
// All inputs/outputs float32.
//
// Algebra: S==1 -> attention out == v = x @ Wv^T (wq,wk dead).
// RX compose additively; CNOTs are XOR basis permutations ->
//   t_j = cos(v_j + rx_j);  qout[0]=t1*...*t7;  qout[w>=1]=t0*...*tw
// out = qout @ Wc^T + bc
//
// R8 post-mortem: ~28us/GEMM across 3 structures, all with 16 serialized
// K-stages; utilization single-digit -> stage-latency-bound. R9: BK=128
// (8 stages), 2 kernels total: k1 = f32-staged GEMM1 + fused quantum +
// side-convert wc->bf16; k2 = async bf16 GEMM2 + bias.

#define BB 2048
#define EN 1024

typedef short s16x8 __attribute__((ext_vector_type(8)));
typedef float f32x4 __attribute__((ext_vector_type(4)));

union Frag { s16x8 v; __hip_bfloat16 h[8]; };

__device__ inline s16x8 cvt_frag(f32x4 lo, f32x4 hi) {
    Frag u;
    #pragma unroll
    for (int j = 0; j < 4; ++j) {
        u.h[j]     = __float2bfloat16(lo[j]);
        u.h[4 + j] = __float2bfloat16(hi[j]);
    }
    return u.v;
}

// async 16B/lane global -> LDS (lds base wave-uniform; HW adds lane*16)
__device__ inline void gll16(const __hip_bfloat16* g, __hip_bfloat16* l) {
    __builtin_amdgcn_global_load_lds(
        (const __attribute__((address_space(1))) void*)g,
        (__attribute__((address_space(3))) void*)l,
        16, 0, 0);
}

// Kernel 1: V = quantum(x @ Wv^T), plus side-convert wc -> wcb (bf16).
// Tile 64x64, BK=128 (8 iters), 512 thr = 8 waves (4m x 2n), wave tile 16x32.
// LDS: 2 buffers x 16384 bf16 (64 KB). Frag-ordered: A tile (mt,kt) at
// (mt*4+kt)*512, B tile (nt,kt) at 8192+(nt*4+kt)*512; lane frag at +lane*8.
__global__ __launch_bounds__(512, 4) void gemm1q_kernel(
        const float* __restrict__ x, const float* __restrict__ wv,
        const float* __restrict__ wc, const float* __restrict__ rx,
        __hip_bfloat16* __restrict__ wcb, __hip_bfloat16* __restrict__ V)
{
    __shared__ __align__(16) __hip_bfloat16 lds[32768];   // 64 KB

    const int tid  = threadIdx.x;
    const int wave = tid >> 6, lane = tid & 63;
    const int l15 = lane & 15, lq = lane >> 4;
    const int m0 = blockIdx.x * 64, n0 = blockIdx.y * 64;
    const int wmt = wave >> 1;          // 0..3
    const int wnt = wave & 1;           // 0..1
    const int bid = blockIdx.x + 32 * blockIdx.y;   // 0..511

    // side job: convert this block's 2048-elem chunk of wc -> wcb
    if (tid < 256) {
        const size_t off = (size_t)bid * 2048 + tid * 8;
        f32x4 lo = *(const f32x4*)(wc + off);
        f32x4 hi = *(const f32x4*)(wc + off + 4);
        *(s16x8*)(wcb + off) = cvt_frag(lo, hi);
    }

    // staging map: thread covers 4 of 32 frag-tiles: t = wave*4 + i
    const float* gsrc[4];
    int ldst[4];
    #pragma unroll
    for (int i = 0; i < 4; ++i) {
        const int t = wave * 4 + i;
        const int kt = t & 3;
        const float* base;
        int row;
        if (t < 16) { base = x;  row = m0 + (t >> 2) * 16 + l15; }
        else        { base = wv; row = n0 + ((t - 16) >> 2) * 16 + l15; }
        gsrc[i] = base + (size_t)row * EN + kt * 32 + lq * 8;
        ldst[i] = t * 512 + lane * 8;
    }

    f32x4 acc[2] = {};
    f32x4 lo[4], hi[4];

    #pragma unroll
    for (int i = 0; i < 4; ++i) { lo[i] = *(const f32x4*)gsrc[i]; hi[i] = *(const f32x4*)(gsrc[i] + 4); }
    #pragma unroll
    for (int i = 0; i < 4; ++i) *(s16x8*)&lds[ldst[i]] = cvt_frag(lo[i], hi[i]);
    __syncthreads();

    int p = 0;
    for (int it = 1; it <= 8; ++it) {
        if (it < 8) {
            #pragma unroll
            for (int i = 0; i < 4; ++i) {
                lo[i] = *(const f32x4*)(gsrc[i] + it * 128);
                hi[i] = *(const f32x4*)(gsrc[i] + it * 128 + 4);
            }
        }
        const __hip_bfloat16* Ab = &lds[p * 16384];
        const __hip_bfloat16* Bb = Ab + 8192;
        #pragma unroll
        for (int kt = 0; kt < 4; ++kt) {
            s16x8 a = *(const s16x8*)&Ab[(wmt * 4 + kt) * 512 + lane * 8];
            #pragma unroll
            for (int j = 0; j < 2; ++j) {
                s16x8 b = *(const s16x8*)&Bb[((wnt * 2 + j) * 4 + kt) * 512 + lane * 8];
                acc[j] = __builtin_amdgcn_mfma_f32_16x16x32_bf16(a, b, acc[j], 0, 0, 0);
            }
        }
        if (it < 8) {
            const int q = p ^ 1;
            #pragma unroll
            for (int i = 0; i < 4; ++i) *(s16x8*)&lds[q * 16384 + ldst[i]] = cvt_frag(lo[i], hi[i]);
        }
        __syncthreads();
        p ^= 1;
    }

    // quantum epilogue: acc -> LDS f32 64x68 -> cos/products -> bf16 V
    float* sb = (float*)lds;                      // 17408 B, K-loop done
    #pragma unroll
    for (int j = 0; j < 2; ++j) {
        const int col = wnt * 32 + j * 16 + l15;
        #pragma unroll
        for (int r = 0; r < 4; ++r)
            sb[(wmt * 16 + lq * 4 + r) * 68 + col] = acc[j][r];
    }
    __syncthreads();
    const int row = tid >> 3, g = tid & 7;        // 64 rows x 8 groups
    const float* pv = &sb[row * 68 + g * 8];
    float t[8];
    #pragma unroll
    for (int j = 0; j < 8; ++j) t[j] = __cosf(pv[j] + rx[j]);
    Frag o;
    float suf = t[1];
    #pragma unroll
    for (int j = 2; j < 8; ++j) suf *= t[j];
    o.h[0] = __float2bfloat16(suf);
    float pr = t[0];
    #pragma unroll
    for (int j = 1; j < 8; ++j) { pr *= t[j]; o.h[j] = __float2bfloat16(pr); }
    *(s16x8*)(V + (size_t)(m0 + row) * EN + n0 + g * 8) = o.v;
}

// Kernel 2: out = V @ Wc^T + bc.  V, wcb bf16 (async staged); out f32.
__global__ __launch_bounds__(512, 4) void gemm2_kernel(
        const __hip_bfloat16* __restrict__ V,
        const __hip_bfloat16* __restrict__ wcb,
        const float* __restrict__ bc, float* __restrict__ out)
{
    __shared__ __align__(16) __hip_bfloat16 lds[32768];   // 64 KB

    const int tid  = threadIdx.x;
    const int wave = tid >> 6, lane = tid & 63;
    const int l15 = lane & 15, lq = lane >> 4;
    const int m0 = blockIdx.x * 64, n0 = blockIdx.y * 64;
    const int wmt = wave >> 1, wnt = wave & 1;

    const __hip_bfloat16* gsrc[4];
    int ldst[4];
    #pragma unroll
    for (int i = 0; i < 4; ++i) {
        const int t = wave * 4 + i;
        const int kt = t & 3;
        const __hip_bfloat16* base;
        int row;
        if (t < 16) { base = V;   row = m0 + (t >> 2) * 16 + l15; }
        else        { base = wcb; row = n0 + ((t - 16) >> 2) * 16 + l15; }
        gsrc[i] = base + (size_t)row * EN + kt * 32 + lq * 8;
        ldst[i] = t * 512;       // wave-uniform; HW adds lane*16B
    }

    f32x4 acc[2] = {};

    #pragma unroll
    for (int i = 0; i < 4; ++i) gll16(gsrc[i], &lds[ldst[i]]);
    __syncthreads();

    int p = 0;
    for (int it = 1; it <= 8; ++it) {
        if (it < 8) {
            const int q = p ^ 1;
            #pragma unroll
            for (int i = 0; i < 4; ++i) gll16(gsrc[i] + it * 128, &lds[q * 16384 + ldst[i]]);
        }
        const __hip_bfloat16* Ab = &lds[p * 16384];
        const __hip_bfloat16* Bb = Ab + 8192;
        #pragma unroll
        for (int kt = 0; kt < 4; ++kt) {
            s16x8 a = *(const s16x8*)&Ab[(wmt * 4 + kt) * 512 + lane * 8];
            #pragma unroll
            for (int j = 0; j < 2; ++j) {
                s16x8 b = *(const s16x8*)&Bb[((wnt * 2 + j) * 4 + kt) * 512 + lane * 8];
                acc[j] = __builtin_amdgcn_mfma_f32_16x16x32_bf16(a, b, acc[j], 0, 0, 0);
            }
        }
        __syncthreads();   // drains vmcnt: next buffer staged; reads of p done
        p ^= 1;
    }

    #pragma unroll
    for (int j = 0; j < 2; ++j) {
        const int col = n0 + wnt * 32 + j * 16 + l15;
        const float bv = bc[col];
        #pragma unroll
        for (int r = 0; r < 4; ++r) {
            const int row = m0 + wmt * 16 + lq * 4 + r;
            out[(size_t)row * EN + col] = acc[j][r] + bv;
        }
    }
}

extern "C" void kernel_launch(void* const* d_in, const int* in_sizes, int n_in,
                              void* d_out, int out_size, void* d_ws, size_t ws_size,
                              hipStream_t stream)
{
    // inputs: x, wq, wk, wv, wc, bc, rx_params (wq/wk dead: S==1)
    const float* x  = (const float*)d_in[0];
    const float* wv = (const float*)d_in[3];
    const float* wc = (const float*)d_in[4];
    const float* bc = (const float*)d_in[5];
    const float* rx = (const float*)d_in[6];
    float* out = (float*)d_out;

    const size_t WE = (size_t)EN * EN;
    // ws (6 MB): [wcb 2MB | V 4MB]
    __hip_bfloat16* wcb = (__hip_bfloat16*)d_ws;
    __hip_bfloat16* V   = wcb + WE;

    dim3 grid(BB / 64, EN / 64);   // 32 x 16 = 512 blocks
    gemm1q_kernel<<<grid, 512, 0, stream>>>(x, wv, wc, rx, wcb, V);
    gemm2_kernel<<<grid, 512, 0, stream>>>(V, wcb, bc, out);
}